// Round 5
// baseline (60.569 us; speedup 1.0000x reference)
//
#include <hip/hip_runtime.h>

// B=4096 tokens, NB=16 branches, S=256 hidden, D=1024.
// out = x + ( relu(x) @ W_in[y]^T + b_in[y] ) @ W_out[y]^T + b_out[y]
// Grouped-GEMM, 3 kernels (no weight-cast pass — f32 weights are cvt'd in staging):
//  K0 setup: 1 block: hist / aligned offsets / perm scatter / tileBranch
//  K1 gemm1: hid = relu(x[perm]) @ W_in^T + b_in   (64x64 tiles, 2-phase dbuf,
//            A and B both reg-staged f32->bf16 with swizzled ds_write)
//  K2 gemm2: out[tok] = x[tok] + hid @ W_out^T + b_out (64x128 tiles, 2-phase dbuf,
//            A=Hp via global_load_lds + pre-swizzled source, B reg-staged f32->bf16,
//            LDS-bounce coalesced epilogue)
// gemm2's staged-buffer publish uses EXPLICIT `s_waitcnt vmcnt(0)` before the barrier
// (global_load_lds publishing contract — R3 lesson). gemm1 has no gload_lds: plain
// __syncthreads suffices (reg->ds_write deps are compiler-tracked).

typedef unsigned short u16;
typedef short bf16x8 __attribute__((ext_vector_type(8)));
typedef float f32x4 __attribute__((ext_vector_type(4)));

#define MFMA16 __builtin_amdgcn_mfma_f32_16x16x32_bf16

constexpr int B_TOK = 4096;
constexpr int NB = 16;
constexpr int S_DIM = 256;
constexpr int D_DIM = 1024;
constexpr int BM = 64;
constexpr int PAD_ROWS = B_TOK + NB * BM;   // 5120
constexpr int NTILES = PAD_ROWS / BM;       // 80

__device__ __forceinline__ unsigned short f2bf(float f) {
    unsigned u = __builtin_bit_cast(unsigned, f);
    u += 0x7fffu + ((u >> 16) & 1u);   // RNE
    return (unsigned short)(u >> 16);
}
__device__ __forceinline__ unsigned pack2(float a, float b) {
    return (unsigned)f2bf(a) | ((unsigned)f2bf(b) << 16);
}
__device__ __forceinline__ void gload_lds16(const void* g, void* l) {
    __builtin_amdgcn_global_load_lds(
        (const __attribute__((address_space(1))) void*)g,
        (__attribute__((address_space(3))) void*)l, 16, 0, 0);
}
// Publish staged LDS when global_load_lds is in flight: drain vmem, then barrier.
__device__ __forceinline__ void publish() {
    asm volatile("s_waitcnt vmcnt(0)" ::: "memory");
    __syncthreads();
}

// ---------------------------------------------------------------------------
// K0: setup — hist, 64-aligned segment offsets, token permutation, tile->branch
// ---------------------------------------------------------------------------
__global__ __launch_bounds__(256) void setup_kernel(
    const int* __restrict__ y, int* __restrict__ perm, int* __restrict__ tileBranch) {
    __shared__ int hist[NB];
    __shared__ int aoff[NB + 1];
    __shared__ int cursor[NB];
    const int t = threadIdx.x;
    if (t < NB) hist[t] = 0;
    __syncthreads();
    for (int i = t; i < B_TOK; i += 256) atomicAdd(&hist[y[i]], 1);
    __syncthreads();
    if (t == 0) {
        int off = 0;
        for (int n = 0; n < NB; ++n) {
            aoff[n] = off;
            cursor[n] = off;
            off += ((hist[n] + BM - 1) / BM) * BM;
        }
        aoff[NB] = off;
    }
    __syncthreads();
    for (int i = t; i < NTILES; i += 256) {
        int rb = i * BM, br = -1;
        for (int n = 0; n < NB; ++n)
            if (rb >= aoff[n] && rb < aoff[n + 1]) br = n;
        tileBranch[i] = br;
    }
    for (int i = t; i < PAD_ROWS; i += 256) perm[i] = -1;
    __syncthreads();
    for (int i = t; i < B_TOK; i += 256) {
        int pos = atomicAdd(&cursor[y[i]], 1);
        perm[pos] = i;
    }
}

// ---------------------------------------------------------------------------
// K1: GEMM1  Hp[5120p,256] = relu(x[perm]) @ W_in[br]^T + b_in   (bf16 out)
// tile 64x64, BK=64, 16 K-steps, 256 thr = 4 waves (2x2 of 32x32 wave-tiles)
// A and B reg-staged (f32 global -> relu/cvt -> swizzled ds_write), 2-phase dbuf.
// ---------------------------------------------------------------------------
__global__ __launch_bounds__(256) void gemm1_kernel(
    const float* __restrict__ x, const float* __restrict__ Wi_f,
    const float* __restrict__ b_in, const int* __restrict__ tileBranch,
    const int* __restrict__ perm, u16* __restrict__ Hp) {
    const int branch = tileBranch[blockIdx.y];
    if (branch < 0) return;
    const int rowBase = blockIdx.y * BM;
    const int colBase = blockIdx.x * 64;

    __shared__ u16 sA[2][64 * 64];   // 8 KB each, XOR-swizzled
    __shared__ u16 sB[2][64 * 64];

    const int t = threadIdx.x;
    const int sr = t >> 2;           // staged row 0..63 (for both A and B)
    const int scg = t & 3;           // 16-elem col group
    const int tok = perm[rowBase + sr];
    const float* aSrc = (tok >= 0) ? (x + (size_t)tok * D_DIM + scg * 16) : x;
    const float* bSrc = Wi_f + ((size_t)branch * S_DIM + colBase + sr) * D_DIM + scg * 16;
    const int sbyte0 = (sr * 128 + scg * 32) ^ ((sr & 7) << 4);
    const int sbyte1 = sbyte0 ^ 16;

    const int lane = t & 63;
    const int wid = t >> 6;
    const int wm = (wid >> 1) * 32;
    const int wn = (wid & 1) * 32;
    const int fr = lane & 15;
    const int kc = (lane >> 4) << 3;

    f32x4 acc[2][2] = {};

    float4 av0, av1, av2, av3, bv0, bv1, bv2, bv3;
    auto loadRegs = [&](int k0) {
        const float4* pa = (const float4*)(aSrc + k0);
        const float4* pb = (const float4*)(bSrc + k0);
        av0 = pa[0]; av1 = pa[1]; av2 = pa[2]; av3 = pa[3];
        bv0 = pb[0]; bv1 = pb[1]; bv2 = pb[2]; bv3 = pb[3];
    };
    auto packWrite = [&](int buf) {
        uint4 wa0, wa1;
        if (tok >= 0) {
            wa0.x = pack2(fmaxf(av0.x, 0.f), fmaxf(av0.y, 0.f));
            wa0.y = pack2(fmaxf(av0.z, 0.f), fmaxf(av0.w, 0.f));
            wa0.z = pack2(fmaxf(av1.x, 0.f), fmaxf(av1.y, 0.f));
            wa0.w = pack2(fmaxf(av1.z, 0.f), fmaxf(av1.w, 0.f));
            wa1.x = pack2(fmaxf(av2.x, 0.f), fmaxf(av2.y, 0.f));
            wa1.y = pack2(fmaxf(av2.z, 0.f), fmaxf(av2.w, 0.f));
            wa1.z = pack2(fmaxf(av3.x, 0.f), fmaxf(av3.y, 0.f));
            wa1.w = pack2(fmaxf(av3.z, 0.f), fmaxf(av3.w, 0.f));
        } else {
            wa0 = make_uint4(0, 0, 0, 0);
            wa1 = make_uint4(0, 0, 0, 0);
        }
        *(uint4*)((char*)sA[buf] + sbyte0) = wa0;
        *(uint4*)((char*)sA[buf] + sbyte1) = wa1;
        uint4 wb0, wb1;
        wb0.x = pack2(bv0.x, bv0.y);
        wb0.y = pack2(bv0.z, bv0.w);
        wb0.z = pack2(bv1.x, bv1.y);
        wb0.w = pack2(bv1.z, bv1.w);
        wb1.x = pack2(bv2.x, bv2.y);
        wb1.y = pack2(bv2.z, bv2.w);
        wb1.z = pack2(bv3.x, bv3.y);
        wb1.w = pack2(bv3.z, bv3.w);
        *(uint4*)((char*)sB[buf] + sbyte0) = wb0;
        *(uint4*)((char*)sB[buf] + sbyte1) = wb1;
    };

    loadRegs(0);
    packWrite(0);
    __syncthreads();

    for (int kt = 0; kt < 16; ++kt) {
        const int cur = kt & 1;
        if (kt < 15) loadRegs((kt + 1) << 6);   // issue early; consumed after compute
#pragma unroll
        for (int kk = 0; kk < 2; ++kk) {
            const int kcol = kc + kk * 32;
            const int ra0 = wm + fr, ra1 = wm + 16 + fr;
            const int rb0 = wn + fr, rb1 = wn + 16 + fr;
            bf16x8 a0 = *(const bf16x8*)&sA[cur][(ra0 * 64 + kcol) ^ ((ra0 & 7) << 3)];
            bf16x8 a1 = *(const bf16x8*)&sA[cur][(ra1 * 64 + kcol) ^ ((ra1 & 7) << 3)];
            bf16x8 b0 = *(const bf16x8*)&sB[cur][(rb0 * 64 + kcol) ^ ((rb0 & 7) << 3)];
            bf16x8 b1 = *(const bf16x8*)&sB[cur][(rb1 * 64 + kcol) ^ ((rb1 & 7) << 3)];
            acc[0][0] = MFMA16(a0, b0, acc[0][0], 0, 0, 0);
            acc[0][1] = MFMA16(a0, b1, acc[0][1], 0, 0, 0);
            acc[1][0] = MFMA16(a1, b0, acc[1][0], 0, 0, 0);
            acc[1][1] = MFMA16(a1, b1, acc[1][1], 0, 0, 0);
        }
        if (kt < 15) packWrite(cur ^ 1);
        __syncthreads();   // publishes next buffer; protects cur from next iter's writes
    }

    const int r0 = (lane >> 4) * 4;
#pragma unroll
    for (int m = 0; m < 2; ++m) {
        const int prow0 = rowBase + wm + m * 16 + r0;
#pragma unroll
        for (int n = 0; n < 2; ++n) {
            const int col = colBase + wn + n * 16 + fr;
            const float bvs = b_in[branch * S_DIM + col];
#pragma unroll
            for (int r = 0; r < 4; ++r)
                Hp[(size_t)(prow0 + r) * S_DIM + col] = f2bf(acc[m][n][r] + bvs);
        }
    }
}

// ---------------------------------------------------------------------------
// K2: GEMM2  out[tok,1024] = x[tok] + Hp @ W_out[br]^T + b_out
// tile 64x128, K=256 (4 K-steps), 2-phase dbuf:
//   A (Hp bf16) via global_load_lds + pre-swizzled source; B reg-staged f32->bf16.
// LDS-bounce coalesced epilogue.
// ---------------------------------------------------------------------------
__global__ __launch_bounds__(256) void gemm2_kernel(
    const u16* __restrict__ Hp, const float* __restrict__ Wo_f,
    const float* __restrict__ b_out, const int* __restrict__ tileBranch,
    const int* __restrict__ perm, const float* __restrict__ x,
    float* __restrict__ out) {
    const int branch = tileBranch[blockIdx.y];
    if (branch < 0) return;
    const int rowBase = blockIdx.y * BM;
    const int colBase = blockIdx.x * 128;

    __shared__ __align__(16) char smem[49152];  // sA[2]8K | sB[2]16K ; bounce 33.8K overlay
    u16* sA0 = (u16*)smem;
    u16* sA1 = (u16*)(smem + 8192);
    u16* sB0 = (u16*)(smem + 16384);
    u16* sB1 = (u16*)(smem + 32768);

    const int t = threadIdx.x;
    const u16* Ab = Hp + (size_t)rowBase * S_DIM;

    // B staging: 128 rows x 64 kcols; thread t handles row t>>1, half (t&1)*32 cols
    const int brow = t >> 1;
    const int bhalf = t & 1;
    const float* bSrc = Wo_f + ((size_t)branch * D_DIM + colBase + brow) * S_DIM + bhalf * 32;
    const int bsw = (brow & 7) << 4;
    const int bbase = brow * 128 + bhalf * 64;

    const int lane = t & 63;
    const int wid = t >> 6;
    const int wm = (wid >> 1) * 32;
    const int wn = (wid & 1) * 64;
    const int fr = lane & 15;
    const int kc = (lane >> 4) << 3;

    f32x4 acc[2][4] = {};

    float4 bv[8];
    auto loadB = [&](int k0) {
        const float4* p = (const float4*)(bSrc + k0);
#pragma unroll
        for (int q = 0; q < 8; ++q) bv[q] = p[q];
    };
    auto writeB = [&](u16* dB) {
#pragma unroll
        for (int q = 0; q < 4; ++q) {
            uint4 w;
            w.x = pack2(bv[2 * q].x, bv[2 * q].y);
            w.y = pack2(bv[2 * q].z, bv[2 * q].w);
            w.z = pack2(bv[2 * q + 1].x, bv[2 * q + 1].y);
            w.w = pack2(bv[2 * q + 1].z, bv[2 * q + 1].w);
            *(uint4*)((char*)dB + ((bbase + q * 16) ^ bsw)) = w;
        }
    };
    auto stageA = [&](u16* dA, int k0) {
#pragma unroll
        for (int i = 0; i < 2; ++i) {
            const int L = i * 4096 + t * 16;
            const int row = L >> 7;
            const int sunit = ((L >> 4) & 7) ^ (row & 7);
            gload_lds16((const char*)Ab + (size_t)row * (S_DIM * 2) + k0 * 2 + sunit * 16,
                        (char*)dA + L);
        }
    };
    auto compute = [&](const u16* cA, const u16* cB) {
#pragma unroll
        for (int kk = 0; kk < 2; ++kk) {
            const int kcol = kc + kk * 32;
            const int ra0 = wm + fr, ra1 = wm + 16 + fr;
            bf16x8 a0 = *(const bf16x8*)&cA[(ra0 * 64 + kcol) ^ ((ra0 & 7) << 3)];
            bf16x8 a1 = *(const bf16x8*)&cA[(ra1 * 64 + kcol) ^ ((ra1 & 7) << 3)];
            bf16x8 b[4];
#pragma unroll
            for (int n = 0; n < 4; ++n) {
                const int rb = wn + n * 16 + fr;
                b[n] = *(const bf16x8*)&cB[(rb * 64 + kcol) ^ ((rb & 7) << 3)];
            }
#pragma unroll
            for (int n = 0; n < 4; ++n) {
                acc[0][n] = MFMA16(a0, b[n], acc[0][n], 0, 0, 0);
                acc[1][n] = MFMA16(a1, b[n], acc[1][n], 0, 0, 0);
            }
        }
    };

    stageA(sA0, 0);
    loadB(0);
    writeB(sB0);
    publish();
#pragma unroll
    for (int kt = 0; kt < 4; ++kt) {
        const bool even = (kt & 1) == 0;
        u16* cA = even ? sA0 : sA1;
        u16* cB = even ? sB0 : sB1;
        u16* nA = even ? sA1 : sA0;
        u16* nB = even ? sB1 : sB0;
        if (kt < 3) {
            stageA(nA, (kt + 1) << 6);
            loadB((kt + 1) << 6);
        }
        compute(cA, cB);
        if (kt < 3) writeB(nB);
        publish();   // vmcnt(0) drains gload_lds (had the MFMA phase to land) + barrier
    }

    // ---- LDS-bounce epilogue: acc -> smem[64][132] f32 -> coalesced stores
    float* bo = (float*)smem;                 // [64][132] padded
    const int r0 = (lane >> 4) * 4;
#pragma unroll
    for (int m = 0; m < 2; ++m)
#pragma unroll
        for (int n = 0; n < 4; ++n)
#pragma unroll
            for (int r = 0; r < 4; ++r)
                bo[(wm + m * 16 + r0 + r) * 132 + wn + n * 16 + fr] = acc[m][n][r];
    __syncthreads();

    const int erow = t >> 2;                  // 0..63
    const int q4 = (t & 3) * 4;               // f32 col base within 16-col group
    const int tok2 = perm[rowBase + erow];
    if (tok2 >= 0) {
        const size_t gbase = (size_t)tok2 * D_DIM + colBase;
        const float* xr = x + gbase;
        float* orow = out + gbase;
        const float* br = b_out + (size_t)branch * D_DIM + colBase;
#pragma unroll
        for (int j = 0; j < 8; ++j) {
            const int c = q4 + j * 16;        // 4 lanes cover 16 consecutive f32
            float4 xv = *(const float4*)&xr[c];
            float4 bvv = *(const float4*)&br[c];
            float4 hv = *(const float4*)&bo[erow * 132 + c];
            float4 s;
            s.x = xv.x + bvv.x + hv.x;
            s.y = xv.y + bvv.y + hv.y;
            s.z = xv.z + bvv.z + hv.z;
            s.w = xv.w + bvv.w + hv.w;
            *(float4*)&orow[c] = s;
        }
    }
}

// ---------------------------------------------------------------------------
extern "C" void kernel_launch(void* const* d_in, const int* in_sizes, int n_in,
                              void* d_out, int out_size, void* d_ws, size_t ws_size,
                              hipStream_t stream) {
    const float* x     = (const float*)d_in[0];
    const int*   y     = (const int*)d_in[1];
    const float* W_in  = (const float*)d_in[2];
    const float* b_in  = (const float*)d_in[3];
    const float* W_out = (const float*)d_in[4];
    const float* b_out = (const float*)d_in[5];
    float* out = (float*)d_out;

    char* ws = (char*)d_ws;
    u16* Hp = (u16*)(ws);                       // 5120*256*2 = 2.62 MB
    int* perm = (int*)(ws + 2621440);           // 5120*4
    int* tileBranch = (int*)(ws + 2641920);     // 80*4

    setup_kernel<<<1, 256, 0, stream>>>(y, perm, tileBranch);

    gemm1_kernel<<<dim3(S_DIM / 64, NTILES), 256, 0, stream>>>(
        x, W_in, b_in, tileBranch, perm, Hp);

    gemm2_kernel<<<dim3(D_DIM / 128, NTILES), 256, 0, stream>>>(
        Hp, W_out, b_out, tileBranch, perm, x, out);
}

// Round 7
// 56.209 us; speedup vs baseline: 1.0776x; 1.0776x over previous
//
#include <hip/hip_runtime.h>

// B=4096 tokens, NB=16 branches, S=256 hidden, D=1024.
// out = x + ( relu(x) @ W_in[y]^T + b_in[y] ) @ W_out[y]^T + b_out[y]
// Grouped-GEMM, 3 dispatches (R4 structure + Wo-cast overlapped into gemm1):
//  K1 prep:  block 0 = setup (hist/offsets/perm/tileBranch); blocks 1..2048 cast W_in
//  K2 gemm1: hid = relu(x[perm]) @ W_in^T + b_in  (64x64 tiles, 2-phase dbuf,
//            A reg-staged x+relu+cvt, B via global_load_lds) + grid-stride tail
//            that casts W_out -> bf16 (consumed only by gemm2; hides in block stagger)
//  K3 gemm2: out[tok] = x[tok] + hid @ W_out^T + b_out (64x128 tiles, 2-phase dbuf,
//            both operands global_load_lds, LDS-bounce coalesced epilogue)
// Publishing contract: EXPLICIT `s_waitcnt vmcnt(0)` before any barrier publishing a
// global_load_lds-staged buffer (R3 lesson: compiler does NOT guarantee the drain).
// LDS bank conflicts: XOR swizzle; gload_lds tiles use linear LDS dest +
// pre-swizzled per-lane global source (m173); reg-staged A writes swizzled directly.
// R6 lesson: hipLaunchCooperativeKernel failed silently (all-zero output) — avoid.

typedef unsigned short u16;
typedef short bf16x8 __attribute__((ext_vector_type(8)));
typedef float f32x4 __attribute__((ext_vector_type(4)));

#define MFMA16 __builtin_amdgcn_mfma_f32_16x16x32_bf16

constexpr int B_TOK = 4096;
constexpr int NB = 16;
constexpr int S_DIM = 256;
constexpr int D_DIM = 1024;
constexpr int BM = 64;
constexpr int PAD_ROWS = B_TOK + NB * BM;   // 5120
constexpr int NTILES = PAD_ROWS / BM;       // 80
constexpr int W_ITEMS = NB * S_DIM * D_DIM / 8;   // 524288 uint4-sized cast items

__device__ __forceinline__ unsigned short f2bf(float f) {
    unsigned u = __builtin_bit_cast(unsigned, f);
    u += 0x7fffu + ((u >> 16) & 1u);   // RNE
    return (unsigned short)(u >> 16);
}
__device__ __forceinline__ unsigned pack2(float a, float b) {
    return (unsigned)f2bf(a) | ((unsigned)f2bf(b) << 16);
}
__device__ __forceinline__ void gload_lds16(const void* g, void* l) {
    __builtin_amdgcn_global_load_lds(
        (const __attribute__((address_space(1))) void*)g,
        (__attribute__((address_space(3))) void*)l, 16, 0, 0);
}
// Publish staged LDS when global_load_lds is in flight: drain vmem, then barrier.
__device__ __forceinline__ void publish() {
    asm volatile("s_waitcnt vmcnt(0)" ::: "memory");
    __syncthreads();
}
// fp32 -> bf16, 8 elems per item j
__device__ __forceinline__ void cast8(const float* __restrict__ src,
                                      u16* __restrict__ dst, int j) {
    const float4* p = (const float4*)src + (size_t)j * 2;
    float4 v0 = p[0], v1 = p[1];
    uint4 o;
    o.x = pack2(v0.x, v0.y);
    o.y = pack2(v0.z, v0.w);
    o.z = pack2(v1.x, v1.y);
    o.w = pack2(v1.z, v1.w);
    ((uint4*)dst)[j] = o;
}

// ---------------------------------------------------------------------------
// K1: setup (block 0) + W_in cast (blocks 1..2048, one uint4 per thread)
// ---------------------------------------------------------------------------
__global__ __launch_bounds__(256) void prep_kernel(
    const float* __restrict__ Wi_f, u16* __restrict__ Wi,
    const int* __restrict__ y, int* __restrict__ perm, int* __restrict__ tileBranch) {
    const int t = threadIdx.x;
    if (blockIdx.x == 0) {
        __shared__ int hist[NB];
        __shared__ int aoff[NB + 1];
        __shared__ int cursor[NB];
        if (t < NB) hist[t] = 0;
        __syncthreads();
        for (int i = t; i < B_TOK; i += 256) atomicAdd(&hist[y[i]], 1);
        __syncthreads();
        if (t == 0) {
            int off = 0;
            for (int n = 0; n < NB; ++n) {
                aoff[n] = off;
                cursor[n] = off;
                off += ((hist[n] + BM - 1) / BM) * BM;
            }
            aoff[NB] = off;
        }
        __syncthreads();
        for (int i = t; i < NTILES; i += 256) {
            int rb = i * BM, br = -1;
            for (int n = 0; n < NB; ++n)
                if (rb >= aoff[n] && rb < aoff[n + 1]) br = n;
            tileBranch[i] = br;
        }
        for (int i = t; i < PAD_ROWS; i += 256) perm[i] = -1;
        __syncthreads();
        for (int i = t; i < B_TOK; i += 256) {
            int pos = atomicAdd(&cursor[y[i]], 1);
            perm[pos] = i;
        }
        return;
    }
    cast8(Wi_f, Wi, (blockIdx.x - 1) * 256 + t);   // 2048*256 == W_ITEMS exactly
}

// ---------------------------------------------------------------------------
// K2: GEMM1  Hp[5120p,256] = relu(x[perm]) @ W_in[br]^T + b_in   (bf16 out)
// tile 64x64, BK=64, 16 K-steps, 256 thr = 4 waves (2x2 of 32x32 wave-tiles)
// 2-phase dbuf. Tail: grid-stride cast of W_out (for gemm2), overlapped.
// ---------------------------------------------------------------------------
__global__ __launch_bounds__(256) void gemm1_kernel(
    const float* __restrict__ x, const u16* __restrict__ Wi,
    const float* __restrict__ b_in, const int* __restrict__ tileBranch,
    const int* __restrict__ perm, u16* __restrict__ Hp,
    const float* __restrict__ Wo_f, u16* __restrict__ Wo) {
    const int branch = tileBranch[blockIdx.y];
    const int t = threadIdx.x;

    if (branch >= 0) {
        const int rowBase = blockIdx.y * BM;
        const int colBase = blockIdx.x * 64;

        __shared__ u16 sA[2][64 * 64];   // 8 KB each, XOR-swizzled
        __shared__ u16 sB[2][64 * 64];   // 8 KB each, swizzled via pre-swizzled source

        // A staging map: 4 threads/row, 16 floats each
        const int sr = t >> 2;
        const int scg = t & 3;
        const int tok = perm[rowBase + sr];
        const float* aSrc = (tok >= 0) ? (x + (size_t)tok * D_DIM + scg * 16) : x;
        const int sbyte0 = (sr * 128 + scg * 32) ^ ((sr & 7) << 4);
        const int sbyte1 = sbyte0 ^ 16;

        const u16* Bb = Wi + (size_t)branch * S_DIM * D_DIM + (size_t)colBase * D_DIM;

        const int lane = t & 63;
        const int wid = t >> 6;
        const int wm = (wid >> 1) * 32;
        const int wn = (wid & 1) * 32;
        const int fr = lane & 15;
        const int kc = (lane >> 4) << 3;

        f32x4 acc[2][2] = {};
        float4 av0, av1, av2, av3;

        auto loadA = [&](int k0) {
            const float4* pa = (const float4*)(aSrc + k0);
            av0 = pa[0]; av1 = pa[1]; av2 = pa[2]; av3 = pa[3];
        };
        auto stageB = [&](int buf, int k0) {
#pragma unroll
            for (int i = 0; i < 2; ++i) {
                const int L = i * 4096 + t * 16;
                const int row = L >> 7;
                const int sunit = ((L >> 4) & 7) ^ (row & 7);
                gload_lds16((const char*)Bb + (size_t)row * (D_DIM * 2) + k0 * 2 + sunit * 16,
                            (char*)sB[buf] + L);
            }
        };
        auto packWriteA = [&](int buf) {
            uint4 w0, w1;
            if (tok >= 0) {
                w0.x = pack2(fmaxf(av0.x, 0.f), fmaxf(av0.y, 0.f));
                w0.y = pack2(fmaxf(av0.z, 0.f), fmaxf(av0.w, 0.f));
                w0.z = pack2(fmaxf(av1.x, 0.f), fmaxf(av1.y, 0.f));
                w0.w = pack2(fmaxf(av1.z, 0.f), fmaxf(av1.w, 0.f));
                w1.x = pack2(fmaxf(av2.x, 0.f), fmaxf(av2.y, 0.f));
                w1.y = pack2(fmaxf(av2.z, 0.f), fmaxf(av2.w, 0.f));
                w1.z = pack2(fmaxf(av3.x, 0.f), fmaxf(av3.y, 0.f));
                w1.w = pack2(fmaxf(av3.z, 0.f), fmaxf(av3.w, 0.f));
            } else {
                w0 = make_uint4(0, 0, 0, 0);
                w1 = make_uint4(0, 0, 0, 0);
            }
            *(uint4*)((char*)sA[buf] + sbyte0) = w0;
            *(uint4*)((char*)sA[buf] + sbyte1) = w1;
        };

        loadA(0);
        stageB(0, 0);
        packWriteA(0);
        publish();

        for (int kt = 0; kt < 16; ++kt) {
            const int cur = kt & 1;
            if (kt < 15) {
                stageB(cur ^ 1, (kt + 1) << 6);
                loadA((kt + 1) << 6);
            }
#pragma unroll
            for (int kk = 0; kk < 2; ++kk) {
                const int kcol = kc + kk * 32;
                const int ra0 = wm + fr, ra1 = wm + 16 + fr;
                const int rb0 = wn + fr, rb1 = wn + 16 + fr;
                bf16x8 a0 = *(const bf16x8*)&sA[cur][(ra0 * 64 + kcol) ^ ((ra0 & 7) << 3)];
                bf16x8 a1 = *(const bf16x8*)&sA[cur][(ra1 * 64 + kcol) ^ ((ra1 & 7) << 3)];
                bf16x8 b0 = *(const bf16x8*)&sB[cur][(rb0 * 64 + kcol) ^ ((rb0 & 7) << 3)];
                bf16x8 b1 = *(const bf16x8*)&sB[cur][(rb1 * 64 + kcol) ^ ((rb1 & 7) << 3)];
                acc[0][0] = MFMA16(a0, b0, acc[0][0], 0, 0, 0);
                acc[0][1] = MFMA16(a0, b1, acc[0][1], 0, 0, 0);
                acc[1][0] = MFMA16(a1, b0, acc[1][0], 0, 0, 0);
                acc[1][1] = MFMA16(a1, b1, acc[1][1], 0, 0, 0);
            }
            if (kt < 15) packWriteA(cur ^ 1);
            publish();   // vmcnt(0) drains stage(kt+1), then barrier publishes
        }

        const int r0 = (lane >> 4) * 4;
#pragma unroll
        for (int m = 0; m < 2; ++m) {
            const int prow0 = rowBase + wm + m * 16 + r0;
#pragma unroll
            for (int n = 0; n < 2; ++n) {
                const int col = colBase + wn + n * 16 + fr;
                const float bvs = b_in[branch * S_DIM + col];
#pragma unroll
                for (int r = 0; r < 4; ++r)
                    Hp[(size_t)(prow0 + r) * S_DIM + col] = f2bf(acc[m][n][r] + bvs);
            }
        }
    }

    // ---- tail: cast W_out -> bf16, grid-strided over the 320 blocks.
    // Consumed only by gemm2 (next dispatch) — overlaps gemm1 block stagger.
    const int bid = blockIdx.y * 4 + blockIdx.x;     // grid is (4, NTILES)
    for (int j = bid * 256 + t; j < W_ITEMS; j += 4 * NTILES * 256)
        cast8(Wo_f, Wo, j);
}

// ---------------------------------------------------------------------------
// K3: GEMM2  out[tok,1024] = x[tok] + Hp @ W_out[br]^T + b_out
// tile 64x128, K=256 (4 K-steps), 2-phase dbuf, LDS-bounce coalesced epilogue
// ---------------------------------------------------------------------------
__global__ __launch_bounds__(256) void gemm2_kernel(
    const u16* __restrict__ Hp, const u16* __restrict__ Wo,
    const float* __restrict__ b_out, const int* __restrict__ tileBranch,
    const int* __restrict__ perm, const float* __restrict__ x,
    float* __restrict__ out) {
    const int branch = tileBranch[blockIdx.y];
    if (branch < 0) return;
    const int rowBase = blockIdx.y * BM;
    const int colBase = blockIdx.x * 128;

    __shared__ __align__(16) char smem[49152];  // sA[2]8K | sB[2]16K ; bounce 33.8K overlay
    u16* sA0 = (u16*)smem;
    u16* sA1 = (u16*)(smem + 8192);
    u16* sB0 = (u16*)(smem + 16384);
    u16* sB1 = (u16*)(smem + 32768);

    const int t = threadIdx.x;
    const u16* Ab = Hp + (size_t)rowBase * S_DIM;
    const u16* Bb = Wo + (size_t)branch * D_DIM * S_DIM + (size_t)colBase * S_DIM;

    const int lane = t & 63;
    const int wid = t >> 6;
    const int wm = (wid >> 1) * 32;
    const int wn = (wid & 1) * 64;
    const int fr = lane & 15;
    const int kc = (lane >> 4) << 3;

    f32x4 acc[2][4] = {};

    auto stage = [&](u16* dA, u16* dB, int k0) {
#pragma unroll
        for (int i = 0; i < 2; ++i) {
            const int L = i * 4096 + t * 16;
            const int row = L >> 7;
            const int sunit = ((L >> 4) & 7) ^ (row & 7);
            gload_lds16((const char*)Ab + (size_t)row * (S_DIM * 2) + k0 * 2 + sunit * 16,
                        (char*)dA + L);
        }
#pragma unroll
        for (int i = 0; i < 4; ++i) {
            const int L = i * 4096 + t * 16;
            const int row = L >> 7;
            const int sunit = ((L >> 4) & 7) ^ (row & 7);
            gload_lds16((const char*)Bb + (size_t)row * (S_DIM * 2) + k0 * 2 + sunit * 16,
                        (char*)dB + L);
        }
    };
    auto compute = [&](const u16* cA, const u16* cB) {
#pragma unroll
        for (int kk = 0; kk < 2; ++kk) {
            const int kcol = kc + kk * 32;
            const int ra0 = wm + fr, ra1 = wm + 16 + fr;
            bf16x8 a0 = *(const bf16x8*)&cA[(ra0 * 64 + kcol) ^ ((ra0 & 7) << 3)];
            bf16x8 a1 = *(const bf16x8*)&cA[(ra1 * 64 + kcol) ^ ((ra1 & 7) << 3)];
            bf16x8 b[4];
#pragma unroll
            for (int n = 0; n < 4; ++n) {
                const int rb = wn + n * 16 + fr;
                b[n] = *(const bf16x8*)&cB[(rb * 64 + kcol) ^ ((rb & 7) << 3)];
            }
#pragma unroll
            for (int n = 0; n < 4; ++n) {
                acc[0][n] = MFMA16(a0, b[n], acc[0][n], 0, 0, 0);
                acc[1][n] = MFMA16(a1, b[n], acc[1][n], 0, 0, 0);
            }
        }
    };

    stage(sA0, sB0, 0);
    publish();
#pragma unroll
    for (int kt = 0; kt < 4; ++kt) {
        const bool even = (kt & 1) == 0;
        u16* cA = even ? sA0 : sA1;
        u16* cB = even ? sB0 : sB1;
        u16* nA = even ? sA1 : sA0;
        u16* nB = even ? sB1 : sB0;
        if (kt < 3) stage(nA, nB, (kt + 1) << 6);
        compute(cA, cB);
        publish();   // vmcnt(0) drains gload_lds (had the MFMA phase to land) + barrier
    }

    // ---- LDS-bounce epilogue: acc -> smem[64][132] f32 -> coalesced stores
    float* bo = (float*)smem;                 // [64][132] padded
    const int r0 = (lane >> 4) * 4;
#pragma unroll
    for (int m = 0; m < 2; ++m)
#pragma unroll
        for (int n = 0; n < 4; ++n)
#pragma unroll
            for (int r = 0; r < 4; ++r)
                bo[(wm + m * 16 + r0 + r) * 132 + wn + n * 16 + fr] = acc[m][n][r];
    __syncthreads();

    const int erow = t >> 2;                  // 0..63
    const int q4 = (t & 3) * 4;               // f32 col base within 16-col group
    const int tok2 = perm[rowBase + erow];
    if (tok2 >= 0) {
        const size_t gbase = (size_t)tok2 * D_DIM + colBase;
        const float* xr = x + gbase;
        float* orow = out + gbase;
        const float* br = b_out + (size_t)branch * D_DIM + colBase;
#pragma unroll
        for (int j = 0; j < 8; ++j) {
            const int c = q4 + j * 16;        // 4 lanes cover 16 consecutive f32
            float4 xv = *(const float4*)&xr[c];
            float4 bvv = *(const float4*)&br[c];
            float4 hv = *(const float4*)&bo[erow * 132 + c];
            float4 s;
            s.x = xv.x + bvv.x + hv.x;
            s.y = xv.y + bvv.y + hv.y;
            s.z = xv.z + bvv.z + hv.z;
            s.w = xv.w + bvv.w + hv.w;
            *(float4*)&orow[c] = s;
        }
    }
}

// ---------------------------------------------------------------------------
extern "C" void kernel_launch(void* const* d_in, const int* in_sizes, int n_in,
                              void* d_out, int out_size, void* d_ws, size_t ws_size,
                              hipStream_t stream) {
    const float* x     = (const float*)d_in[0];
    const int*   y     = (const int*)d_in[1];
    const float* W_in  = (const float*)d_in[2];
    const float* b_in  = (const float*)d_in[3];
    const float* W_out = (const float*)d_in[4];
    const float* b_out = (const float*)d_in[5];
    float* out = (float*)d_out;

    char* ws = (char*)d_ws;
    u16* Wi = (u16*)(ws);                       // 8 MB
    u16* Wo = (u16*)(ws + 8388608);             // 8 MB
    u16* Hp = (u16*)(ws + 16777216);            // 2.62 MB
    int* perm = (int*)(ws + 19398656);          // 5120*4
    int* tileBranch = (int*)(ws + 19419136);    // 80*4

    prep_kernel<<<2049, 256, 0, stream>>>(W_in, Wi, y, perm, tileBranch);

    gemm1_kernel<<<dim3(S_DIM / 64, NTILES), 256, 0, stream>>>(
        x, Wi, b_in, tileBranch, perm, Hp, W_out, Wo);

    gemm2_kernel<<<dim3(D_DIM / 128, NTILES), 256, 0, stream>>>(
        Hp, Wo, b_out, tileBranch, perm, x, out);
}

// Round 8
// 55.346 us; speedup vs baseline: 1.0944x; 1.0156x over previous
//
#include <hip/hip_runtime.h>

// B=4096 tokens, NB=16 branches, S=256 hidden, D=1024.
// out = x + ( relu(x) @ W_in[y]^T + b_in[y] ) @ W_out[y]^T + b_out[y]
// Grouped-GEMM, 4 dispatches — R7 lesson: gemm1 was a 42us latency-bound whale
// (320 blocks = 1.25/CU, occupancy 8.7%, HBM 1.2 TB/s). Fix = parallelism:
//  K1 prep:   block 0 = setup; blocks 1..4096 cast W_in+W_out -> bf16
//  K2 gemm1:  K-split x4 -> 1280 blocks (5/CU). Each: 64x64 tile, 4 K-steps
//             over a 256-K chunk, 2-phase dbuf, f32 partials to Hpart[4][.][.]
//  K3 reduce: Hp = bf16( sum_ks Hpart + b_in )  (640 blocks, streaming)
//  K4 gemm2:  64x64 tiles -> 1280 blocks (5/CU), K=256, 2-phase dbuf,
//             LDS-bounce coalesced epilogue with bias + residual scatter
// Publishing contract: EXPLICIT `s_waitcnt vmcnt(0)` before any barrier that
// publishes a global_load_lds-staged buffer (R3 lesson).
// LDS bank conflicts: XOR swizzle; gload_lds tiles use linear LDS dest +
// pre-swizzled per-lane global source (m173); reg-staged A writes swizzled.

typedef unsigned short u16;
typedef short bf16x8 __attribute__((ext_vector_type(8)));
typedef float f32x4 __attribute__((ext_vector_type(4)));

#define MFMA16 __builtin_amdgcn_mfma_f32_16x16x32_bf16

constexpr int B_TOK = 4096;
constexpr int NB = 16;
constexpr int S_DIM = 256;
constexpr int D_DIM = 1024;
constexpr int BM = 64;
constexpr int PAD_ROWS = B_TOK + NB * BM;    // 5120
constexpr int NTILES = PAD_ROWS / BM;        // 80
constexpr int KSPLIT = 4;                    // gemm1 K-chunks (1024/4 = 256)
constexpr int HP_ELEMS = PAD_ROWS * S_DIM;   // 1310720 per k-chunk

__device__ __forceinline__ unsigned short f2bf(float f) {
    unsigned u = __builtin_bit_cast(unsigned, f);
    u += 0x7fffu + ((u >> 16) & 1u);   // RNE
    return (unsigned short)(u >> 16);
}
__device__ __forceinline__ unsigned pack2(float a, float b) {
    return (unsigned)f2bf(a) | ((unsigned)f2bf(b) << 16);
}
__device__ __forceinline__ void gload_lds16(const void* g, void* l) {
    __builtin_amdgcn_global_load_lds(
        (const __attribute__((address_space(1))) void*)g,
        (__attribute__((address_space(3))) void*)l, 16, 0, 0);
}
// Publish staged LDS: drain all vmem (incl. global_load_lds), then barrier.
__device__ __forceinline__ void publish() {
    asm volatile("s_waitcnt vmcnt(0)" ::: "memory");
    __syncthreads();
}
// fp32 -> bf16, 8 elems per item j
__device__ __forceinline__ void cast8(const float* __restrict__ src,
                                      u16* __restrict__ dst, int j) {
    const float4* p = (const float4*)src + (size_t)j * 2;
    float4 v0 = p[0], v1 = p[1];
    uint4 o;
    o.x = pack2(v0.x, v0.y);
    o.y = pack2(v0.z, v0.w);
    o.z = pack2(v1.x, v1.y);
    o.w = pack2(v1.z, v1.w);
    ((uint4*)dst)[j] = o;
}

// ---------------------------------------------------------------------------
// K1: setup (block 0) + W casts (blocks 1..4096)
// ---------------------------------------------------------------------------
__global__ __launch_bounds__(256) void prep_kernel(
    const float* __restrict__ Wi_f, const float* __restrict__ Wo_f,
    u16* __restrict__ Wi, u16* __restrict__ Wo,
    const int* __restrict__ y, int* __restrict__ perm, int* __restrict__ tileBranch) {
    const int t = threadIdx.x;
    if (blockIdx.x == 0) {
        __shared__ int hist[NB];
        __shared__ int aoff[NB + 1];
        __shared__ int cursor[NB];
        if (t < NB) hist[t] = 0;
        __syncthreads();
        for (int i = t; i < B_TOK; i += 256) atomicAdd(&hist[y[i]], 1);
        __syncthreads();
        if (t == 0) {
            int off = 0;
            for (int n = 0; n < NB; ++n) {
                aoff[n] = off;
                cursor[n] = off;
                off += ((hist[n] + BM - 1) / BM) * BM;
            }
            aoff[NB] = off;
        }
        __syncthreads();
        for (int i = t; i < NTILES; i += 256) {
            int rb = i * BM, br = -1;
            for (int n = 0; n < NB; ++n)
                if (rb >= aoff[n] && rb < aoff[n + 1]) br = n;
            tileBranch[i] = br;
        }
        for (int i = t; i < PAD_ROWS; i += 256) perm[i] = -1;
        __syncthreads();
        for (int i = t; i < B_TOK; i += 256) {
            int pos = atomicAdd(&cursor[y[i]], 1);
            perm[pos] = i;
        }
        return;
    }
    int i = (blockIdx.x - 1) * 256 + t;          // 0 .. 1048575
    if (i < 524288) cast8(Wi_f, Wi, i);
    else            cast8(Wo_f, Wo, i - 524288);
}

// ---------------------------------------------------------------------------
// K2: GEMM1 partials.  Hpart[ks][5120p,256] = relu(x[perm]) @ W_in[br]^T
// grid (4 col, 80 row, 4 kchunk) = 1280 blocks. 64x64 tile, BK=64, 4 K-steps.
// A reg-staged (x gather + relu + cvt, swizzled ds_write); B via gload_lds.
// ---------------------------------------------------------------------------
__global__ __launch_bounds__(256) void gemm1_kernel(
    const float* __restrict__ x, const u16* __restrict__ Wi,
    const int* __restrict__ tileBranch, const int* __restrict__ perm,
    float* __restrict__ Hpart) {
    const int branch = tileBranch[blockIdx.y];
    if (branch < 0) return;
    const int rowBase = blockIdx.y * BM;
    const int colBase = blockIdx.x * 64;
    const int kbase = blockIdx.z * (D_DIM / KSPLIT);   // 0,256,512,768

    __shared__ u16 sA[2][64 * 64];   // 8 KB each, XOR-swizzled
    __shared__ u16 sB[2][64 * 64];

    const int t = threadIdx.x;
    // A staging map: 4 threads/row, 16 floats each
    const int sr = t >> 2;
    const int scg = t & 3;
    const int tok = perm[rowBase + sr];
    const float* aSrc = (tok >= 0) ? (x + (size_t)tok * D_DIM + scg * 16) : x;
    const int sbyte0 = (sr * 128 + scg * 32) ^ ((sr & 7) << 4);
    const int sbyte1 = sbyte0 ^ 16;

    const u16* Bb = Wi + (size_t)branch * S_DIM * D_DIM + (size_t)colBase * D_DIM;

    const int lane = t & 63;
    const int wid = t >> 6;
    const int wm = (wid >> 1) * 32;
    const int wn = (wid & 1) * 32;
    const int fr = lane & 15;
    const int kc = (lane >> 4) << 3;

    f32x4 acc[2][2] = {};
    float4 av0, av1, av2, av3;

    auto loadA = [&](int k0) {
        const float4* pa = (const float4*)(aSrc + k0);
        av0 = pa[0]; av1 = pa[1]; av2 = pa[2]; av3 = pa[3];
    };
    auto stageB = [&](int buf, int k0) {
#pragma unroll
        for (int i = 0; i < 2; ++i) {
            const int L = i * 4096 + t * 16;
            const int row = L >> 7;
            const int sunit = ((L >> 4) & 7) ^ (row & 7);
            gload_lds16((const char*)Bb + (size_t)row * (D_DIM * 2) + k0 * 2 + sunit * 16,
                        (char*)sB[buf] + L);
        }
    };
    auto packWriteA = [&](int buf) {
        uint4 w0, w1;
        if (tok >= 0) {
            w0.x = pack2(fmaxf(av0.x, 0.f), fmaxf(av0.y, 0.f));
            w0.y = pack2(fmaxf(av0.z, 0.f), fmaxf(av0.w, 0.f));
            w0.z = pack2(fmaxf(av1.x, 0.f), fmaxf(av1.y, 0.f));
            w0.w = pack2(fmaxf(av1.z, 0.f), fmaxf(av1.w, 0.f));
            w1.x = pack2(fmaxf(av2.x, 0.f), fmaxf(av2.y, 0.f));
            w1.y = pack2(fmaxf(av2.z, 0.f), fmaxf(av2.w, 0.f));
            w1.z = pack2(fmaxf(av3.x, 0.f), fmaxf(av3.y, 0.f));
            w1.w = pack2(fmaxf(av3.z, 0.f), fmaxf(av3.w, 0.f));
        } else {
            w0 = make_uint4(0, 0, 0, 0);
            w1 = make_uint4(0, 0, 0, 0);
        }
        *(uint4*)((char*)sA[buf] + sbyte0) = w0;
        *(uint4*)((char*)sA[buf] + sbyte1) = w1;
    };

    loadA(kbase);
    stageB(0, kbase);
    packWriteA(0);
    publish();

    for (int kt = 0; kt < 4; ++kt) {
        const int cur = kt & 1;
        if (kt < 3) {
            const int k0n = kbase + ((kt + 1) << 6);
            stageB(cur ^ 1, k0n);
            loadA(k0n);
        }
#pragma unroll
        for (int kk = 0; kk < 2; ++kk) {
            const int kcol = kc + kk * 32;
            const int ra0 = wm + fr, ra1 = wm + 16 + fr;
            const int rb0 = wn + fr, rb1 = wn + 16 + fr;
            bf16x8 a0 = *(const bf16x8*)&sA[cur][(ra0 * 64 + kcol) ^ ((ra0 & 7) << 3)];
            bf16x8 a1 = *(const bf16x8*)&sA[cur][(ra1 * 64 + kcol) ^ ((ra1 & 7) << 3)];
            bf16x8 b0 = *(const bf16x8*)&sB[cur][(rb0 * 64 + kcol) ^ ((rb0 & 7) << 3)];
            bf16x8 b1 = *(const bf16x8*)&sB[cur][(rb1 * 64 + kcol) ^ ((rb1 & 7) << 3)];
            acc[0][0] = MFMA16(a0, b0, acc[0][0], 0, 0, 0);
            acc[0][1] = MFMA16(a0, b1, acc[0][1], 0, 0, 0);
            acc[1][0] = MFMA16(a1, b0, acc[1][0], 0, 0, 0);
            acc[1][1] = MFMA16(a1, b1, acc[1][1], 0, 0, 0);
        }
        if (kt < 3) packWriteA(cur ^ 1);
        publish();   // vmcnt(0) drains stage(kt+1), then barrier publishes
    }

    float* Op = Hpart + (size_t)blockIdx.z * HP_ELEMS;
    const int r0 = (lane >> 4) * 4;
#pragma unroll
    for (int m = 0; m < 2; ++m) {
        const int prow0 = rowBase + wm + m * 16 + r0;
#pragma unroll
        for (int n = 0; n < 2; ++n) {
            const int col = colBase + wn + n * 16 + fr;
#pragma unroll
            for (int r = 0; r < 4; ++r)
                Op[(size_t)(prow0 + r) * S_DIM + col] = acc[m][n][r];
        }
    }
}

// ---------------------------------------------------------------------------
// K3: reduce — Hp[row,col] = bf16( sum_ks Hpart[ks][row,col] + b_in[br][col] )
// 640 blocks x 256 thr, 8 cols per thread.
// ---------------------------------------------------------------------------
__global__ __launch_bounds__(256) void reduce_kernel(
    const float* __restrict__ Hpart, const float* __restrict__ b_in,
    const int* __restrict__ tileBranch, u16* __restrict__ Hp) {
    const int j = blockIdx.x * 256 + threadIdx.x;   // 0 .. 163839
    const int row = j >> 5;
    const int c8 = (j & 31) << 3;
    const int branch = tileBranch[row >> 6];
    if (branch < 0) return;
    const float* p = Hpart + (size_t)row * S_DIM + c8;
    float4 s0 = *(const float4*)p;
    float4 s1 = *(const float4*)(p + 4);
#pragma unroll
    for (int ks = 1; ks < KSPLIT; ++ks) {
        const float* q = p + (size_t)ks * HP_ELEMS;
        float4 a0 = *(const float4*)q;
        float4 a1 = *(const float4*)(q + 4);
        s0.x += a0.x; s0.y += a0.y; s0.z += a0.z; s0.w += a0.w;
        s1.x += a1.x; s1.y += a1.y; s1.z += a1.z; s1.w += a1.w;
    }
    const float* bp = b_in + (size_t)branch * S_DIM + c8;
    float4 b0 = *(const float4*)bp;
    float4 b1 = *(const float4*)(bp + 4);
    uint4 o;
    o.x = pack2(s0.x + b0.x, s0.y + b0.y);
    o.y = pack2(s0.z + b0.z, s0.w + b0.w);
    o.z = pack2(s1.x + b1.x, s1.y + b1.y);
    o.w = pack2(s1.z + b1.z, s1.w + b1.w);
    *(uint4*)&Hp[(size_t)row * S_DIM + c8] = o;
}

// ---------------------------------------------------------------------------
// K4: GEMM2  out[tok,1024] = x[tok] + Hp @ W_out[br]^T + b_out
// 64x64 tiles -> grid (16, 80) = 1280 blocks. K=256 (4 steps), 2-phase dbuf,
// both operands via gload_lds, LDS-bounce coalesced epilogue.
// ---------------------------------------------------------------------------
__global__ __launch_bounds__(256) void gemm2_kernel(
    const u16* __restrict__ Hp, const u16* __restrict__ Wo,
    const float* __restrict__ b_out, const int* __restrict__ tileBranch,
    const int* __restrict__ perm, const float* __restrict__ x,
    float* __restrict__ out) {
    const int branch = tileBranch[blockIdx.y];
    if (branch < 0) return;
    const int rowBase = blockIdx.y * BM;
    const int colBase = blockIdx.x * 64;

    __shared__ __align__(16) char smem[32768];  // sA[2]8K | sB[2]8K ; bounce 17.4K overlay
    u16* sA0 = (u16*)smem;
    u16* sA1 = (u16*)(smem + 8192);
    u16* sB0 = (u16*)(smem + 16384);
    u16* sB1 = (u16*)(smem + 24576);

    const int t = threadIdx.x;
    const u16* Ab = Hp + (size_t)rowBase * S_DIM;
    const u16* Bb = Wo + (size_t)branch * D_DIM * S_DIM + (size_t)colBase * S_DIM;

    const int lane = t & 63;
    const int wid = t >> 6;
    const int wm = (wid >> 1) * 32;
    const int wn = (wid & 1) * 32;
    const int fr = lane & 15;
    const int kc = (lane >> 4) << 3;

    f32x4 acc[2][2] = {};

    auto stage = [&](u16* dA, u16* dB, int k0) {
#pragma unroll
        for (int i = 0; i < 2; ++i) {
            const int L = i * 4096 + t * 16;
            const int row = L >> 7;
            const int sunit = ((L >> 4) & 7) ^ (row & 7);
            gload_lds16((const char*)Ab + (size_t)row * (S_DIM * 2) + k0 * 2 + sunit * 16,
                        (char*)dA + L);
        }
#pragma unroll
        for (int i = 0; i < 2; ++i) {
            const int L = i * 4096 + t * 16;
            const int row = L >> 7;
            const int sunit = ((L >> 4) & 7) ^ (row & 7);
            gload_lds16((const char*)Bb + (size_t)row * (S_DIM * 2) + k0 * 2 + sunit * 16,
                        (char*)dB + L);
        }
    };
    auto compute = [&](const u16* cA, const u16* cB) {
#pragma unroll
        for (int kk = 0; kk < 2; ++kk) {
            const int kcol = kc + kk * 32;
            const int ra0 = wm + fr, ra1 = wm + 16 + fr;
            const int rb0 = wn + fr, rb1 = wn + 16 + fr;
            bf16x8 a0 = *(const bf16x8*)&cA[(ra0 * 64 + kcol) ^ ((ra0 & 7) << 3)];
            bf16x8 a1 = *(const bf16x8*)&cA[(ra1 * 64 + kcol) ^ ((ra1 & 7) << 3)];
            bf16x8 b0 = *(const bf16x8*)&cB[(rb0 * 64 + kcol) ^ ((rb0 & 7) << 3)];
            bf16x8 b1 = *(const bf16x8*)&cB[(rb1 * 64 + kcol) ^ ((rb1 & 7) << 3)];
            acc[0][0] = MFMA16(a0, b0, acc[0][0], 0, 0, 0);
            acc[0][1] = MFMA16(a0, b1, acc[0][1], 0, 0, 0);
            acc[1][0] = MFMA16(a1, b0, acc[1][0], 0, 0, 0);
            acc[1][1] = MFMA16(a1, b1, acc[1][1], 0, 0, 0);
        }
    };

    stage(sA0, sB0, 0);
    publish();
#pragma unroll
    for (int kt = 0; kt < 4; ++kt) {
        const bool even = (kt & 1) == 0;
        u16* cA = even ? sA0 : sA1;
        u16* cB = even ? sB0 : sB1;
        u16* nA = even ? sA1 : sA0;
        u16* nB = even ? sB1 : sB0;
        if (kt < 3) stage(nA, nB, (kt + 1) << 6);
        compute(cA, cB);
        publish();   // vmcnt(0) drains gload_lds (had the MFMA phase to land) + barrier
    }

    // ---- LDS-bounce epilogue: acc -> smem[64][68] f32 -> coalesced stores
    float* bo = (float*)smem;
    const int r0 = (lane >> 4) * 4;
#pragma unroll
    for (int m = 0; m < 2; ++m)
#pragma unroll
        for (int n = 0; n < 2; ++n)
#pragma unroll
            for (int r = 0; r < 4; ++r)
                bo[(wm + m * 16 + r0 + r) * 68 + wn + n * 16 + fr] = acc[m][n][r];
    __syncthreads();

    const int erow = t >> 2;                  // 0..63
    const int q4 = (t & 3) * 4;               // f32 col base within 16-col group
    const int tok2 = perm[rowBase + erow];
    if (tok2 >= 0) {
        const size_t gbase = (size_t)tok2 * D_DIM + colBase;
        const float* xr = x + gbase;
        float* orow = out + gbase;
        const float* br = b_out + (size_t)branch * D_DIM + colBase;
#pragma unroll
        for (int j = 0; j < 4; ++j) {
            const int c = q4 + j * 16;        // 4 lanes cover 16 consecutive f32
            float4 xv = *(const float4*)&xr[c];
            float4 bvv = *(const float4*)&br[c];
            float4 hv = *(const float4*)&bo[erow * 68 + c];
            float4 s;
            s.x = xv.x + bvv.x + hv.x;
            s.y = xv.y + bvv.y + hv.y;
            s.z = xv.z + bvv.z + hv.z;
            s.w = xv.w + bvv.w + hv.w;
            *(float4*)&orow[c] = s;
        }
    }
}

// ---------------------------------------------------------------------------
extern "C" void kernel_launch(void* const* d_in, const int* in_sizes, int n_in,
                              void* d_out, int out_size, void* d_ws, size_t ws_size,
                              hipStream_t stream) {
    const float* x     = (const float*)d_in[0];
    const int*   y     = (const int*)d_in[1];
    const float* W_in  = (const float*)d_in[2];
    const float* b_in  = (const float*)d_in[3];
    const float* W_out = (const float*)d_in[4];
    const float* b_out = (const float*)d_in[5];
    float* out = (float*)d_out;

    char* ws = (char*)d_ws;
    u16* Wi = (u16*)(ws);                        // 8 MB
    u16* Wo = (u16*)(ws + 8388608);              // 8 MB
    u16* Hp = (u16*)(ws + 16777216);             // 2.62 MB
    float* Hpart = (float*)(ws + 19398656);      // 4 * 5.24 MB = 20.97 MB
    int* perm = (int*)(ws + 40370176);           // 5120*4
    int* tileBranch = (int*)(ws + 40390656);     // 80*4

    prep_kernel<<<4097, 256, 0, stream>>>(W_in, W_out, Wi, Wo, y, perm, tileBranch);

    gemm1_kernel<<<dim3(4, NTILES, KSPLIT), 256, 0, stream>>>(
        x, Wi, tileBranch, perm, Hpart);

    reduce_kernel<<<640, 256, 0, stream>>>(Hpart, b_in, tileBranch, Hp);

    gemm2_kernel<<<dim3(16, NTILES), 256, 0, stream>>>(
        Hp, Wo, b_out, tileBranch, perm, x, out);
}